// Round 5
// baseline (643.756 us; speedup 1.0000x reference)
//
#include <hip/hip_runtime.h>

#define AS1 __attribute__((address_space(1)))
#define AS3 __attribute__((address_space(3)))

typedef unsigned short u16;
typedef unsigned int u32;
typedef __attribute__((ext_vector_type(8))) _Float16 half8;
typedef __attribute__((ext_vector_type(4))) u16 u16x4;
typedef __attribute__((ext_vector_type(2))) u32 u32x2;
typedef __attribute__((ext_vector_type(4))) float f32x4;

__device__ __forceinline__ u16 f2h(float f) {
    _Float16 h = (_Float16)f;
    return __builtin_bit_cast(u16, h);
}

__device__ __forceinline__ u32 pk2h(float a, float b) {
    return __builtin_bit_cast(u32, __builtin_amdgcn_cvt_pkrtz(a, b));
}

__device__ __forceinline__ float fexp2(float x) {
#if __has_builtin(__builtin_amdgcn_exp2f)
    return __builtin_amdgcn_exp2f(x);
#else
    return __expf(x * 0.69314718055994531f);
#endif
}

// async global->LDS, 16B per lane. LDS dest must be waveBase + lane*16.
__device__ __forceinline__ void async16(const void* g, void* l) {
    __builtin_amdgcn_global_load_lds((AS1 void*)g, (AS3 void*)l, 16, 0, 0);
}

// ---------------- prologue: casts ----------------

__global__ void cast_f32_to_f16(const float* __restrict__ in, u16* __restrict__ out) {
    int i = (blockIdx.x * 256 + threadIdx.x) * 4;
    float4 v = *(const float4*)(in + i);
    u16x4 o = { f2h(v.x), f2h(v.y), f2h(v.z), f2h(v.w) };
    *(u16x4*)(out + i) = o;
}

// in: [K][N] fp32  ->  out: [N][K] fp16, scaled
__global__ void transpose_cast(const float* __restrict__ in, u16* __restrict__ out,
                               int K, int N, float scale) {
    __shared__ float tile[32][33];
    int nb = blockIdx.x * 32, kb = blockIdx.y * 32;
    int tx = threadIdx.x & 31, ty = threadIdx.x >> 5;   // 32 x 8
#pragma unroll
    for (int r = ty; r < 32; r += 8)
        tile[r][tx] = in[(size_t)(kb + r) * N + nb + tx];
    __syncthreads();
#pragma unroll
    for (int r = ty; r < 32; r += 8)
        out[(size_t)(nb + r) * K + kb + tx] = f2h(tile[tx][r] * scale);
}

// ---------------- GEMM: C[M,N] = A[M,K] * Bt[N,K]^T ----------------
// OUTMODE: 0 = fp32, 1 = fp16, 2 = fp16 transposed, 3 = fused KV (n<512 ->
// fp16 into C (ldc 512), n>=512 -> fp16 transposed into C2 (ldc 4096))

template <int OUTMODE>
__global__ __launch_bounds__(256, 2) void gemm_bt(const u16* __restrict__ A,
                                                  const u16* __restrict__ Bt,
                                                  void* __restrict__ C,
                                                  void* __restrict__ C2,
                                                  int M, int N, int K, int ldc) {
    __shared__ __align__(16) u16 As[128 * 32];
    __shared__ __align__(16) u16 Bs[128 * 32];
    const int m0 = blockIdx.x * 128, n0 = blockIdx.y * 128;
    const int wave = threadIdx.x >> 6, lane = threadIdx.x & 63;
    const int quad = lane >> 4, mm = lane & 15;
    const int wm = (wave >> 1) * 64, wn = (wave & 1) * 64;

    const int srow = wave * 16 + (lane >> 2);
    const int scol = 8 * ((lane & 3) ^ ((lane >> 3) & 3));  // XOR chunk swizzle

    const u16* ag0 = A + (size_t)(m0 + srow) * K + scol;
    const u16* ag1 = A + (size_t)(m0 + 64 + srow) * K + scol;
    const u16* bg0 = Bt + (size_t)(n0 + srow) * K + scol;
    const u16* bg1 = Bt + (size_t)(n0 + 64 + srow) * K + scol;
    u16* al0 = As + wave * 512 + lane * 8;
    u16* al1 = As + 64 * 32 + wave * 512 + lane * 8;
    u16* bl0 = Bs + wave * 512 + lane * 8;
    u16* bl1 = Bs + 64 * 32 + wave * 512 + lane * 8;

    f32x4 acc[4][4] = {};
    const int swz = (mm >> 1) & 3;

    for (int k0 = 0; k0 < K; k0 += 32) {
        __syncthreads();
        async16(ag0, al0);
        async16(ag1, al1);
        async16(bg0, bl0);
        async16(bg1, bl1);
        ag0 += 32; ag1 += 32; bg0 += 32; bg1 += 32;
        __syncthreads();
        half8 af[4], bf[4];
#pragma unroll
        for (int i = 0; i < 4; i++)
            af[i] = *(const half8*)(As + (wm + i * 16 + mm) * 32 + (quad ^ swz) * 8);
#pragma unroll
        for (int i = 0; i < 4; i++)
            bf[i] = *(const half8*)(Bs + (wn + i * 16 + mm) * 32 + (quad ^ swz) * 8);
#pragma unroll
        for (int mi = 0; mi < 4; mi++)
#pragma unroll
            for (int ni = 0; ni < 4; ni++)
                acc[mi][ni] = __builtin_amdgcn_mfma_f32_16x16x32_f16(
                    af[mi], bf[ni], acc[mi][ni], 0, 0, 0);
    }

    if (OUTMODE == 0) {
        float* Cp = (float*)C;
#pragma unroll
        for (int mi = 0; mi < 4; mi++)
#pragma unroll
            for (int r = 0; r < 4; r++) {
                float* rp = Cp + (size_t)(m0 + wm + mi * 16 + quad * 4 + r) * ldc + n0 + wn + mm;
#pragma unroll
                for (int ni = 0; ni < 4; ni++) rp[ni * 16] = acc[mi][ni][r];
            }
    } else if (OUTMODE == 1) {
        u16* Cp = (u16*)C;
#pragma unroll
        for (int mi = 0; mi < 4; mi++)
#pragma unroll
            for (int r = 0; r < 4; r++) {
                u16* rp = Cp + (size_t)(m0 + wm + mi * 16 + quad * 4 + r) * ldc + n0 + wn + mm;
#pragma unroll
                for (int ni = 0; ni < 4; ni++) rp[ni * 16] = f2h(acc[mi][ni][r]);
            }
    } else if (OUTMODE == 2) {
        u16* Cp = (u16*)C;
#pragma unroll
        for (int mi = 0; mi < 4; mi++)
#pragma unroll
            for (int r = 0; r < 4; r++) {
                int row = m0 + wm + mi * 16 + quad * 4 + r;
#pragma unroll
                for (int ni = 0; ni < 4; ni++)
                    Cp[(size_t)(n0 + wn + ni * 16 + mm) * ldc + row] = f2h(acc[mi][ni][r]);
            }
    } else {  // fused KV
        if (n0 < 512) {
            u16* Cp = (u16*)C;   // Kb, ldc 512
#pragma unroll
            for (int mi = 0; mi < 4; mi++)
#pragma unroll
                for (int r = 0; r < 4; r++) {
                    u16* rp = Cp + (size_t)(m0 + wm + mi * 16 + quad * 4 + r) * 512 + n0 + wn + mm;
#pragma unroll
                    for (int ni = 0; ni < 4; ni++) rp[ni * 16] = f2h(acc[mi][ni][r]);
                }
        } else {
            u16* Cp = (u16*)C2;  // Vtb, ldc 4096, transposed
#pragma unroll
            for (int mi = 0; mi < 4; mi++)
#pragma unroll
                for (int r = 0; r < 4; r++) {
                    int row = m0 + wm + mi * 16 + quad * 4 + r;
#pragma unroll
                    for (int ni = 0; ni < 4; ni++)
                        Cp[(size_t)(n0 - 512 + wn + ni * 16 + mm) * 4096 + row] = f2h(acc[mi][ni][r]);
                }
        }
    }
}

// ---------------- flash attention v4 -------------------------------------
// SPLIT-way partition over keys; fixed-max softmax makes partials additive.
// qt-serial P round-trip (halved Ps -> 27.6 KB LDS -> 5 blocks/CU).
// Qb pre-scaled by 0.125*log2e. grid (16, 32, 2*SPLIT), 256 thr, wave=32 q.

template <int SPLIT>
__global__ __launch_bounds__(256, 5) void attn_fwd(const u16* __restrict__ Qb,
                                                   const u16* __restrict__ Kb,
                                                   const u16* __restrict__ Vtb,
                                                   u16* __restrict__ Ob,
                                                   float* __restrict__ Of0,
                                                   float* __restrict__ Of1,
                                                   float* __restrict__ Lf) {
    __shared__ __align__(16) u16 Ks[64][72];       // [key][dim]
    __shared__ __align__(16) u16 Vs[64][72];       // [dim][key]
    __shared__ __align__(16) u16 Ps[4][16][72];    // per-wave, per-qt [query][key]

    const int qtb = blockIdx.x, head = blockIdx.y;
    const int b = blockIdx.z & 1, sp = blockIdx.z >> 1;
    const int kvh = head >> 2;
    const int wave = threadIdx.x >> 6, lane = threadIdx.x & 63;
    const int quad = lane >> 4, mm = lane & 15;
    const int t = threadIdx.x;

    const size_t qrow0 = (size_t)b * 2048 + qtb * 128 + wave * 32;
    const int s_beg = sp * (2048 / SPLIT), s_end = s_beg + 2048 / SPLIT;

    // Q fragments, in regs for the whole kernel
    half8 qf[2][2];
#pragma unroll
    for (int qt = 0; qt < 2; qt++)
#pragma unroll
        for (int ks = 0; ks < 2; ks++)
            qf[qt][ks] = *(const half8*)(Qb + (qrow0 + qt * 16 + mm) * 2048 +
                                         head * 64 + ks * 32 + quad * 8);

    f32x4 accO[4][2] = {};
    float lp[2] = {0.f, 0.f};

    // staging: thread t covers rows (t>>3), (t>>3)+32, chunk t&7
    const int srow = t >> 3, sch = t & 7;
    const u16* kg = Kb + ((size_t)b * 2048 + srow) * 512 + kvh * 64 + sch * 8;
    const u16* vg = Vtb + ((size_t)kvh * 64 + srow) * 4096 + b * 2048 + sch * 8;

    half8 kpre[2], vpre[2];
#pragma unroll
    for (int p = 0; p < 2; p++) {
        kpre[p] = *(const half8*)(kg + (size_t)(s_beg + p * 32) * 512);
        vpre[p] = *(const half8*)(vg + s_beg + (size_t)p * 32 * 4096);
    }

    for (int s0 = s_beg; s0 < s_end; s0 += 64) {
        __syncthreads();   // prev-iter readers done
#pragma unroll
        for (int p = 0; p < 2; p++) {
            *(half8*)(&Ks[srow + p * 32][sch * 8]) = kpre[p];
            *(half8*)(&Vs[srow + p * 32][sch * 8]) = vpre[p];
        }
        __syncthreads();   // tile visible

        int sn = s0 + 64;
        if (sn == s_end) sn = s_beg;   // harmless refetch on last iter
#pragma unroll
        for (int p = 0; p < 2; p++) {
            kpre[p] = *(const half8*)(kg + (size_t)(sn + p * 32) * 512);
            vpre[p] = *(const half8*)(vg + sn + (size_t)p * 32 * 4096);
        }

#pragma unroll
        for (int qt = 0; qt < 2; qt++) {
            // S^T = K Q^T, C-init = -10 (fixed softmax max, log2 domain)
            f32x4 accST[4];
#pragma unroll
            for (int kt = 0; kt < 4; kt++)
                accST[kt] = f32x4{-10.f, -10.f, -10.f, -10.f};
#pragma unroll
            for (int ks = 0; ks < 2; ks++)
#pragma unroll
                for (int kt = 0; kt < 4; kt++) {
                    half8 kf = *(const half8*)(&Ks[kt * 16 + mm][ks * 32 + quad * 8]);
                    accST[kt] = __builtin_amdgcn_mfma_f32_16x16x32_f16(
                        kf, qf[qt][ks], accST[kt], 0, 0, 0);
                }

            // p = 2^accST; pack 4 keys -> one b64 LDS write per kt
#pragma unroll
            for (int kt = 0; kt < 4; kt++) {
                float p0 = fexp2(accST[kt][0]);
                float p1 = fexp2(accST[kt][1]);
                float p2 = fexp2(accST[kt][2]);
                float p3 = fexp2(accST[kt][3]);
                lp[qt] += (p0 + p1) + (p2 + p3);
                u32x2 w = { pk2h(p0, p1), pk2h(p2, p3) };
                *(u32x2*)(&Ps[wave][mm][kt * 16 + quad * 4]) = w;
            }
            // same-wave in-order LDS: write->read ordering handled via lgkmcnt

            // O^T += V^T P^T
#pragma unroll
            for (int ks = 0; ks < 2; ks++) {
                half8 pf = *(const half8*)(&Ps[wave][mm][ks * 32 + quad * 8]);
#pragma unroll
                for (int mt = 0; mt < 4; mt++) {
                    half8 vf = *(const half8*)(&Vs[mt * 16 + mm][ks * 32 + quad * 8]);
                    accO[mt][qt] = __builtin_amdgcn_mfma_f32_16x16x32_f16(
                        vf, pf, accO[mt][qt], 0, 0, 0);
                }
            }
        }
    }

    // l reduction across quads (lanes mm, mm+16, mm+32, mm+48)
#pragma unroll
    for (int qt = 0; qt < 2; qt++) {
        float l = lp[qt];
        l += __shfl_xor(l, 16);
        l += __shfl_xor(l, 32);

        if (SPLIT == 1) {
            float inv = 1.f / l;
#pragma unroll
            for (int mt = 0; mt < 4; mt++) {
                u16x4 o = { f2h(accO[mt][qt][0] * inv), f2h(accO[mt][qt][1] * inv),
                            f2h(accO[mt][qt][2] * inv), f2h(accO[mt][qt][3] * inv) };
                *(u16x4*)(Ob + (qrow0 + qt * 16 + mm) * 2048 + head * 64 +
                          mt * 16 + quad * 4) = o;
            }
        } else {
            float* Op = sp ? Of1 : Of0;
            size_t token = qrow0 + qt * 16 + mm;
#pragma unroll
            for (int mt = 0; mt < 4; mt++)
                *(f32x4*)(Op + token * 2048 + head * 64 + mt * 16 + quad * 4) = accO[mt][qt];
            if (quad == 0)
                Lf[((size_t)sp * 4096 + token) * 32 + head] = l;
        }
    }
}

// combine: Ob = (Of0 + Of1) / (l0 + l1), fp16 out
__global__ void attn_combine(const float* __restrict__ Of0, const float* __restrict__ Of1,
                             const float* __restrict__ Lf, u16* __restrict__ Ob) {
    size_t idx = (size_t)blockIdx.x * 256 + threadIdx.x;
    size_t token = idx >> 9;
    int dq = (int)(idx & 511) * 4;
    int head = dq >> 6;
    float inv = 1.f / (Lf[token * 32 + head] + Lf[(4096 + token) * 32 + head]);
    float4 a = *(const float4*)(Of0 + token * 2048 + dq);
    float4 c = *(const float4*)(Of1 + token * 2048 + dq);
    u16x4 o = { f2h((a.x + c.x) * inv), f2h((a.y + c.y) * inv),
                f2h((a.z + c.z) * inv), f2h((a.w + c.w) * inv) };
    *(u16x4*)(Ob + token * 2048 + dq) = o;
}

// ---------------- launch ----------------

extern "C" void kernel_launch(void* const* d_in, const int* in_sizes, int n_in,
                              void* d_out, int out_size, void* d_ws, size_t ws_size,
                              hipStream_t stream) {
    (void)in_sizes; (void)n_in; (void)out_size;
    const float* x  = (const float*)d_in[0];
    const float* Wq = (const float*)d_in[1];
    const float* Wk = (const float*)d_in[2];
    const float* Wv = (const float*)d_in[3];
    const float* Wo = (const float*)d_in[4];
    float* out = (float*)d_out;

    u16* ws = (u16*)d_ws;
    u16* xb   = ws;                              // [4096][2048]
    u16* Wqt  = xb   + (size_t)4096 * 2048;      // [2048][2048]
    u16* Wkvt = Wqt  + (size_t)2048 * 2048;      // [1024][2048] (K rows 0-511, V rows 512-1023)
    u16* Wot  = Wkvt + (size_t)1024 * 2048;      // [2048][2048]
    u16* Qb   = Wot  + (size_t)2048 * 2048;      // [4096][2048]
    u16* Kb   = Qb   + (size_t)4096 * 2048;      // [4096][512]
    u16* Vtb  = Kb   + (size_t)4096 * 512;       // [512][4096]
    u16* Ob   = Vtb  + (size_t)512 * 4096;       // [4096][2048]
    u16* wend = Ob   + (size_t)4096 * 2048;
    float* Of1 = (float*)wend;                            // 33.5 MB
    float* Lf  = (float*)((char*)Of1 + (size_t)4096 * 2048 * 4);  // 1 MB
    size_t need = (size_t)((char*)Lf - (char*)d_ws) + (size_t)2 * 4096 * 32 * 4;
    const bool split = ws_size >= need;

    // fold softmax scale (1/8) and log2(e) into Wq
    const float qscale = 0.125f * 1.4426950408889634f;

    cast_f32_to_f16<<<8192, 256, 0, stream>>>(x, xb);
    transpose_cast<<<dim3(64, 64), 256, 0, stream>>>(Wq, Wqt, 2048, 2048, qscale);
    transpose_cast<<<dim3(16, 64), 256, 0, stream>>>(Wk, Wkvt, 2048, 512, 1.f);
    transpose_cast<<<dim3(16, 64), 256, 0, stream>>>(Wv, Wkvt + (size_t)512 * 2048, 2048, 512, 1.f);
    transpose_cast<<<dim3(64, 64), 256, 0, stream>>>(Wo, Wot, 2048, 2048, 1.f);

    gemm_bt<1><<<dim3(32, 16), 256, 0, stream>>>(xb, Wqt, Qb, nullptr, 4096, 2048, 2048, 2048);
    gemm_bt<3><<<dim3(32, 8),  256, 0, stream>>>(xb, Wkvt, Kb, Vtb, 4096, 1024, 2048, 512);

    if (split) {
        attn_fwd<2><<<dim3(16, 32, 4), 256, 0, stream>>>(Qb, Kb, Vtb, Ob, out, Of1, Lf);
        attn_combine<<<8192, 256, 0, stream>>>(out, Of1, Lf, Ob);
    } else {
        attn_fwd<1><<<dim3(16, 32, 2), 256, 0, stream>>>(Qb, Kb, Vtb, Ob, nullptr, nullptr, nullptr);
    }

    gemm_bt<0><<<dim3(32, 16), 256, 0, stream>>>(Ob, Wot, out, nullptr, 4096, 2048, 2048, 2048);
}

// Round 6
// 382.249 us; speedup vs baseline: 1.6841x; 1.6841x over previous
//
#include <hip/hip_runtime.h>

#define AS1 __attribute__((address_space(1)))
#define AS3 __attribute__((address_space(3)))

typedef unsigned short u16;
typedef unsigned int u32;
typedef __attribute__((ext_vector_type(8))) _Float16 half8;
typedef __attribute__((ext_vector_type(4))) u16 u16x4;
typedef __attribute__((ext_vector_type(2))) u32 u32x2;
typedef __attribute__((ext_vector_type(4))) float f32x4;

__device__ __forceinline__ u16 f2h(float f) {
    _Float16 h = (_Float16)f;
    return __builtin_bit_cast(u16, h);
}

__device__ __forceinline__ u32 pk2h(float a, float b) {
    return __builtin_bit_cast(u32, __builtin_amdgcn_cvt_pkrtz(a, b));
}

__device__ __forceinline__ float fexp2(float x) {
#if __has_builtin(__builtin_amdgcn_exp2f)
    return __builtin_amdgcn_exp2f(x);
#else
    return __expf(x * 0.69314718055994531f);
#endif
}

// async global->LDS, 16B per lane. LDS dest must be waveBase + lane*16.
__device__ __forceinline__ void async16(const void* g, void* l) {
    __builtin_amdgcn_global_load_lds((AS1 void*)g, (AS3 void*)l, 16, 0, 0);
}

// ---------------- prologue: casts ----------------

__global__ void cast_f32_to_f16(const float* __restrict__ in, u16* __restrict__ out) {
    int i = (blockIdx.x * 256 + threadIdx.x) * 4;
    float4 v = *(const float4*)(in + i);
    u16x4 o = { f2h(v.x), f2h(v.y), f2h(v.z), f2h(v.w) };
    *(u16x4*)(out + i) = o;
}

// in: [K][N] fp32  ->  out: [N][K] fp16, scaled
__global__ void transpose_cast(const float* __restrict__ in, u16* __restrict__ out,
                               int K, int N, float scale) {
    __shared__ float tile[32][33];
    int nb = blockIdx.x * 32, kb = blockIdx.y * 32;
    int tx = threadIdx.x & 31, ty = threadIdx.x >> 5;   // 32 x 8
#pragma unroll
    for (int r = ty; r < 32; r += 8)
        tile[r][tx] = in[(size_t)(kb + r) * N + nb + tx];
    __syncthreads();
#pragma unroll
    for (int r = ty; r < 32; r += 8)
        out[(size_t)(nb + r) * K + kb + tx] = f2h(tile[tx][r] * scale);
}

// ---------------- GEMM: C[M,N] = A[M,K] * Bt[N,K]^T ----------------
// OUTMODE: 0 = fp32, 1 = fp16, 2 = fp16 transposed, 3 = fused KV (n<512 ->
// fp16 into C (ldc 512), n>=512 -> fp16 transposed into C2 (ldc 4096))

template <int OUTMODE>
__global__ __launch_bounds__(256, 2) void gemm_bt(const u16* __restrict__ A,
                                                  const u16* __restrict__ Bt,
                                                  void* __restrict__ C,
                                                  void* __restrict__ C2,
                                                  int M, int N, int K, int ldc) {
    __shared__ __align__(16) u16 As[128 * 32];
    __shared__ __align__(16) u16 Bs[128 * 32];
    const int m0 = blockIdx.x * 128, n0 = blockIdx.y * 128;
    const int wave = threadIdx.x >> 6, lane = threadIdx.x & 63;
    const int quad = lane >> 4, mm = lane & 15;
    const int wm = (wave >> 1) * 64, wn = (wave & 1) * 64;

    const int srow = wave * 16 + (lane >> 2);
    const int scol = 8 * ((lane & 3) ^ ((lane >> 3) & 3));  // XOR chunk swizzle

    const u16* ag0 = A + (size_t)(m0 + srow) * K + scol;
    const u16* ag1 = A + (size_t)(m0 + 64 + srow) * K + scol;
    const u16* bg0 = Bt + (size_t)(n0 + srow) * K + scol;
    const u16* bg1 = Bt + (size_t)(n0 + 64 + srow) * K + scol;
    u16* al0 = As + wave * 512 + lane * 8;
    u16* al1 = As + 64 * 32 + wave * 512 + lane * 8;
    u16* bl0 = Bs + wave * 512 + lane * 8;
    u16* bl1 = Bs + 64 * 32 + wave * 512 + lane * 8;

    f32x4 acc[4][4] = {};
    const int swz = (mm >> 1) & 3;

    for (int k0 = 0; k0 < K; k0 += 32) {
        __syncthreads();
        async16(ag0, al0);
        async16(ag1, al1);
        async16(bg0, bl0);
        async16(bg1, bl1);
        ag0 += 32; ag1 += 32; bg0 += 32; bg1 += 32;
        __syncthreads();
        half8 af[4], bf[4];
#pragma unroll
        for (int i = 0; i < 4; i++)
            af[i] = *(const half8*)(As + (wm + i * 16 + mm) * 32 + (quad ^ swz) * 8);
#pragma unroll
        for (int i = 0; i < 4; i++)
            bf[i] = *(const half8*)(Bs + (wn + i * 16 + mm) * 32 + (quad ^ swz) * 8);
#pragma unroll
        for (int mi = 0; mi < 4; mi++)
#pragma unroll
            for (int ni = 0; ni < 4; ni++)
                acc[mi][ni] = __builtin_amdgcn_mfma_f32_16x16x32_f16(
                    af[mi], bf[ni], acc[mi][ni], 0, 0, 0);
    }

    if (OUTMODE == 0) {
        float* Cp = (float*)C;
#pragma unroll
        for (int mi = 0; mi < 4; mi++)
#pragma unroll
            for (int r = 0; r < 4; r++) {
                float* rp = Cp + (size_t)(m0 + wm + mi * 16 + quad * 4 + r) * ldc + n0 + wn + mm;
#pragma unroll
                for (int ni = 0; ni < 4; ni++) rp[ni * 16] = acc[mi][ni][r];
            }
    } else if (OUTMODE == 1) {
        u16* Cp = (u16*)C;
#pragma unroll
        for (int mi = 0; mi < 4; mi++)
#pragma unroll
            for (int r = 0; r < 4; r++) {
                u16* rp = Cp + (size_t)(m0 + wm + mi * 16 + quad * 4 + r) * ldc + n0 + wn + mm;
#pragma unroll
                for (int ni = 0; ni < 4; ni++) rp[ni * 16] = f2h(acc[mi][ni][r]);
            }
    } else if (OUTMODE == 2) {
        u16* Cp = (u16*)C;
#pragma unroll
        for (int mi = 0; mi < 4; mi++)
#pragma unroll
            for (int r = 0; r < 4; r++) {
                int row = m0 + wm + mi * 16 + quad * 4 + r;
#pragma unroll
                for (int ni = 0; ni < 4; ni++)
                    Cp[(size_t)(n0 + wn + ni * 16 + mm) * ldc + row] = f2h(acc[mi][ni][r]);
            }
    } else {  // fused KV
        if (n0 < 512) {
            u16* Cp = (u16*)C;   // Kb, ldc 512
#pragma unroll
            for (int mi = 0; mi < 4; mi++)
#pragma unroll
                for (int r = 0; r < 4; r++) {
                    u16* rp = Cp + (size_t)(m0 + wm + mi * 16 + quad * 4 + r) * 512 + n0 + wn + mm;
#pragma unroll
                    for (int ni = 0; ni < 4; ni++) rp[ni * 16] = f2h(acc[mi][ni][r]);
                }
        } else {
            u16* Cp = (u16*)C2;  // Vtb, ldc 4096, transposed
#pragma unroll
            for (int mi = 0; mi < 4; mi++)
#pragma unroll
                for (int r = 0; r < 4; r++) {
                    int row = m0 + wm + mi * 16 + quad * 4 + r;
#pragma unroll
                    for (int ni = 0; ni < 4; ni++)
                        Cp[(size_t)(n0 - 512 + wn + ni * 16 + mm) * 4096 + row] = f2h(acc[mi][ni][r]);
                }
        }
    }
}

// ---------------- flash attention v5 -------------------------------------
// SPLIT-way key partition (fixed-max softmax -> partials additive).
// qt-serial P round-trip, 27.6 KB LDS. launch_bounds(256,4): 128 reg/wave --
// (256,5) forced accumulator spill (R5: 938 MB scratch writes, 374 us).
// Qb pre-scaled by 0.125*log2e. grid (16, 32, 2*SPLIT), 256 thr, wave=32 q.

template <int SPLIT>
__global__ __launch_bounds__(256, 4) void attn_fwd(const u16* __restrict__ Qb,
                                                   const u16* __restrict__ Kb,
                                                   const u16* __restrict__ Vtb,
                                                   u16* __restrict__ Ob,
                                                   float* __restrict__ Of0,
                                                   float* __restrict__ Of1,
                                                   float* __restrict__ Lf) {
    __shared__ __align__(16) u16 Ks[64][72];       // [key][dim]
    __shared__ __align__(16) u16 Vs[64][72];       // [dim][key]
    __shared__ __align__(16) u16 Ps[4][16][72];    // per-wave, per-qt [query][key]

    const int qtb = blockIdx.x, head = blockIdx.y;
    const int b = blockIdx.z & 1, sp = blockIdx.z >> 1;
    const int kvh = head >> 2;
    const int wave = threadIdx.x >> 6, lane = threadIdx.x & 63;
    const int quad = lane >> 4, mm = lane & 15;
    const int t = threadIdx.x;

    const size_t qrow0 = (size_t)b * 2048 + qtb * 128 + wave * 32;
    const int s_beg = sp * (2048 / SPLIT), s_end = s_beg + 2048 / SPLIT;

    // Q fragments, in regs for the whole kernel
    half8 qf[2][2];
#pragma unroll
    for (int qt = 0; qt < 2; qt++)
#pragma unroll
        for (int ks = 0; ks < 2; ks++)
            qf[qt][ks] = *(const half8*)(Qb + (qrow0 + qt * 16 + mm) * 2048 +
                                         head * 64 + ks * 32 + quad * 8);

    f32x4 accO[4][2] = {};
    float lp[2] = {0.f, 0.f};

    // staging: thread t covers rows (t>>3), (t>>3)+32, chunk t&7
    const int srow = t >> 3, sch = t & 7;
    const u16* kg = Kb + ((size_t)b * 2048 + srow) * 512 + kvh * 64 + sch * 8;
    const u16* vg = Vtb + ((size_t)kvh * 64 + srow) * 4096 + b * 2048 + sch * 8;

    half8 kpre[2], vpre[2];
#pragma unroll
    for (int p = 0; p < 2; p++) {
        kpre[p] = *(const half8*)(kg + (size_t)(s_beg + p * 32) * 512);
        vpre[p] = *(const half8*)(vg + s_beg + (size_t)p * 32 * 4096);
    }

    for (int s0 = s_beg; s0 < s_end; s0 += 64) {
        __syncthreads();   // prev-iter readers done
#pragma unroll
        for (int p = 0; p < 2; p++) {
            *(half8*)(&Ks[srow + p * 32][sch * 8]) = kpre[p];
            *(half8*)(&Vs[srow + p * 32][sch * 8]) = vpre[p];
        }
        __syncthreads();   // tile visible

        int sn = s0 + 64;
        if (sn == s_end) sn = s_beg;   // harmless refetch on last iter
#pragma unroll
        for (int p = 0; p < 2; p++) {
            kpre[p] = *(const half8*)(kg + (size_t)(sn + p * 32) * 512);
            vpre[p] = *(const half8*)(vg + sn + (size_t)p * 32 * 4096);
        }

#pragma unroll
        for (int qt = 0; qt < 2; qt++) {
            // S^T = K Q^T, C-init = -10 (fixed softmax max, log2 domain)
            f32x4 accST[4];
#pragma unroll
            for (int kt = 0; kt < 4; kt++)
                accST[kt] = f32x4{-10.f, -10.f, -10.f, -10.f};
#pragma unroll
            for (int ks = 0; ks < 2; ks++)
#pragma unroll
                for (int kt = 0; kt < 4; kt++) {
                    half8 kf = *(const half8*)(&Ks[kt * 16 + mm][ks * 32 + quad * 8]);
                    accST[kt] = __builtin_amdgcn_mfma_f32_16x16x32_f16(
                        kf, qf[qt][ks], accST[kt], 0, 0, 0);
                }

            // p = 2^accST; pack 4 keys -> one b64 LDS write per kt
#pragma unroll
            for (int kt = 0; kt < 4; kt++) {
                float p0 = fexp2(accST[kt][0]);
                float p1 = fexp2(accST[kt][1]);
                float p2 = fexp2(accST[kt][2]);
                float p3 = fexp2(accST[kt][3]);
                lp[qt] += (p0 + p1) + (p2 + p3);
                u32x2 w = { pk2h(p0, p1), pk2h(p2, p3) };
                *(u32x2*)(&Ps[wave][mm][kt * 16 + quad * 4]) = w;
            }
            // same-wave in-order LDS: write->read ordering handled via lgkmcnt

            // O^T += V^T P^T
#pragma unroll
            for (int ks = 0; ks < 2; ks++) {
                half8 pf = *(const half8*)(&Ps[wave][mm][ks * 32 + quad * 8]);
#pragma unroll
                for (int mt = 0; mt < 4; mt++) {
                    half8 vf = *(const half8*)(&Vs[mt * 16 + mm][ks * 32 + quad * 8]);
                    accO[mt][qt] = __builtin_amdgcn_mfma_f32_16x16x32_f16(
                        vf, pf, accO[mt][qt], 0, 0, 0);
                }
            }
        }
    }

    // l reduction across quads (lanes mm, mm+16, mm+32, mm+48)
#pragma unroll
    for (int qt = 0; qt < 2; qt++) {
        float l = lp[qt];
        l += __shfl_xor(l, 16);
        l += __shfl_xor(l, 32);

        if (SPLIT == 1) {
            float inv = 1.f / l;
#pragma unroll
            for (int mt = 0; mt < 4; mt++) {
                u16x4 o = { f2h(accO[mt][qt][0] * inv), f2h(accO[mt][qt][1] * inv),
                            f2h(accO[mt][qt][2] * inv), f2h(accO[mt][qt][3] * inv) };
                *(u16x4*)(Ob + (qrow0 + qt * 16 + mm) * 2048 + head * 64 +
                          mt * 16 + quad * 4) = o;
            }
        } else {
            float* Op = sp ? Of1 : Of0;
            size_t token = qrow0 + qt * 16 + mm;
#pragma unroll
            for (int mt = 0; mt < 4; mt++)
                *(f32x4*)(Op + token * 2048 + head * 64 + mt * 16 + quad * 4) = accO[mt][qt];
            if (quad == 0)
                Lf[((size_t)sp * 4096 + token) * 32 + head] = l;
        }
    }
}

// combine: Ob = (Of0 + Of1) / (l0 + l1), fp16 out
__global__ void attn_combine(const float* __restrict__ Of0, const float* __restrict__ Of1,
                             const float* __restrict__ Lf, u16* __restrict__ Ob) {
    size_t idx = (size_t)blockIdx.x * 256 + threadIdx.x;
    size_t token = idx >> 9;
    int dq = (int)(idx & 511) * 4;
    int head = dq >> 6;
    float inv = 1.f / (Lf[token * 32 + head] + Lf[(4096 + token) * 32 + head]);
    float4 a = *(const float4*)(Of0 + token * 2048 + dq);
    float4 c = *(const float4*)(Of1 + token * 2048 + dq);
    u16x4 o = { f2h((a.x + c.x) * inv), f2h((a.y + c.y) * inv),
                f2h((a.z + c.z) * inv), f2h((a.w + c.w) * inv) };
    *(u16x4*)(Ob + token * 2048 + dq) = o;
}

// ---------------- launch ----------------

extern "C" void kernel_launch(void* const* d_in, const int* in_sizes, int n_in,
                              void* d_out, int out_size, void* d_ws, size_t ws_size,
                              hipStream_t stream) {
    (void)in_sizes; (void)n_in; (void)out_size;
    const float* x  = (const float*)d_in[0];
    const float* Wq = (const float*)d_in[1];
    const float* Wk = (const float*)d_in[2];
    const float* Wv = (const float*)d_in[3];
    const float* Wo = (const float*)d_in[4];
    float* out = (float*)d_out;

    u16* ws = (u16*)d_ws;
    u16* xb   = ws;                              // [4096][2048]
    u16* Wqt  = xb   + (size_t)4096 * 2048;      // [2048][2048]
    u16* Wkvt = Wqt  + (size_t)2048 * 2048;      // [1024][2048] (K rows 0-511, V rows 512-1023)
    u16* Wot  = Wkvt + (size_t)1024 * 2048;      // [2048][2048]
    u16* Qb   = Wot  + (size_t)2048 * 2048;      // [4096][2048]
    u16* Kb   = Qb   + (size_t)4096 * 2048;      // [4096][512]
    u16* Vtb  = Kb   + (size_t)4096 * 512;       // [512][4096]
    u16* Ob   = Vtb  + (size_t)512 * 4096;       // [4096][2048]
    u16* wend = Ob   + (size_t)4096 * 2048;
    float* Of1 = (float*)wend;                            // 33.5 MB
    float* Lf  = (float*)((char*)Of1 + (size_t)4096 * 2048 * 4);  // 1 MB
    size_t need = (size_t)((char*)Lf - (char*)d_ws) + (size_t)2 * 4096 * 32 * 4;
    const bool split = ws_size >= need;

    // fold softmax scale (1/8) and log2(e) into Wq
    const float qscale = 0.125f * 1.4426950408889634f;

    cast_f32_to_f16<<<8192, 256, 0, stream>>>(x, xb);
    transpose_cast<<<dim3(64, 64), 256, 0, stream>>>(Wq, Wqt, 2048, 2048, qscale);
    transpose_cast<<<dim3(16, 64), 256, 0, stream>>>(Wk, Wkvt, 2048, 512, 1.f);
    transpose_cast<<<dim3(16, 64), 256, 0, stream>>>(Wv, Wkvt + (size_t)512 * 2048, 2048, 512, 1.f);
    transpose_cast<<<dim3(64, 64), 256, 0, stream>>>(Wo, Wot, 2048, 2048, 1.f);

    gemm_bt<1><<<dim3(32, 16), 256, 0, stream>>>(xb, Wqt, Qb, nullptr, 4096, 2048, 2048, 2048);
    gemm_bt<3><<<dim3(32, 8),  256, 0, stream>>>(xb, Wkvt, Kb, Vtb, 4096, 1024, 2048, 512);

    if (split) {
        attn_fwd<2><<<dim3(16, 32, 4), 256, 0, stream>>>(Qb, Kb, Vtb, Ob, out, Of1, Lf);
        attn_combine<<<8192, 256, 0, stream>>>(out, Of1, Lf, Ob);
    } else {
        attn_fwd<1><<<dim3(16, 32, 2), 256, 0, stream>>>(Qb, Kb, Vtb, Ob, nullptr, nullptr, nullptr);
    }

    gemm_bt<0><<<dim3(32, 16), 256, 0, stream>>>(Ob, Wot, out, nullptr, 4096, 2048, 2048, 2048);
}